// Round 12
// baseline (132.577 us; speedup 1.0000x reference)
//
#include <hip/hip_runtime.h>

// GATraj fused kernels for MI355X (gfx950) — round 12.
//
// Math simplifications (verified passing rounds 1-11):
//  * LN over the size-1 W_a channel == be_a exactly -> Pos uniform 1/cnt_i
//    (or 1/768 if relu(be_a)==0 or cnt==0). W_a/b_a/g_a unused.
//  * tmp @ W_g splits; h_i/h_j parts precomputed (A_pre, BH).
//  * r-LayerNorm analytic via 6 moments of centered W_r (KT table).
//
// Round-12 (r11 post-mortem: gat <39.6us (pin worked); top-5 now all harness
// poison-fill — controllable budget is gat+prep):
//  * prep: K-split GEMV — 768 blocks x 4 waves/row (16 fmas/wave + LDS
//    reduce) instead of 193 blocks with a 64-deep serial fma chain
//    (0.75 blocks/CU was occupancy-starved)
//  * gat: constant loads (KT/Bf/GB/A_pre) hoisted to kernel entry so their
//    latency overlaps the compaction barriers; next-tile l4/cc LDS prefetch

#define NN 768
#define DD 64
#define EPSF 1e-5f
#define LOG2E 1.44269504f

typedef __attribute__((ext_vector_type(8))) short short8;
typedef __attribute__((ext_vector_type(4))) float float4v;
typedef __attribute__((ext_vector_type(2))) float float2v;
typedef __attribute__((ext_vector_type(4))) unsigned short ushort4v;

__device__ __forceinline__ unsigned short f2bf(float f) {
  unsigned int u = __float_as_uint(f);
  u += 0x7fffu + ((u >> 16) & 1u);  // round-to-nearest-even
  return (unsigned short)(u >> 16);
}

__device__ __forceinline__ float fast_tanh(float x) {
  float e = __builtin_amdgcn_exp2f(fminf(x, 20.f) * (2.f * LOG2E));
  return (e - 1.f) * __builtin_amdgcn_rcpf(e + 1.f);
}

// ---------------------------------------------------------------------------
// Prep kernel, grid = 769 blocks x 256 threads:
//   bid < 768  : row bid's A_pre/BH GEMV, K-split across 4 waves (wave w
//                covers k in [16w,16w+16)) + LDS reduce
//   bid == 768 : transposed bf16 Wg_lo pack + W_r moments -> KT/GB/evec
// ---------------------------------------------------------------------------
__global__ __launch_bounds__(256) void prep_kernel(
    const float* __restrict__ hidden, const float* __restrict__ Wg,
    const float* __restrict__ bg, const float* __restrict__ Wr,
    const float* __restrict__ br, const float* __restrict__ gr,
    const float* __restrict__ ber, const float* __restrict__ gg,
    const float* __restrict__ beg, float* __restrict__ A_pre,
    float2v* __restrict__ BH, float4v* __restrict__ KT,
    float2v* __restrict__ GB, float* __restrict__ evec,
    unsigned short* __restrict__ WgT) {
  const int bid = blockIdx.x;
  const int tid = threadIdx.x;

  if (bid == NN) {
    for (int idx = tid; idx < DD * DD; idx += 256) {
      int n = idx >> 6, k = idx & 63;
      WgT[idx] = f2bf(Wg[k * DD + n]);
    }
    if (tid < 64) {  // wave 0: W_r moments, KT, GB, evec
      int t = tid;
      float w0 = Wr[t], w1 = Wr[DD + t], bb = br[t];
      float m0 = w0, m1 = w1, mb = bb;
      for (int m = 1; m < 64; m <<= 1) {
        m0 += __shfl_xor(m0, m);
        m1 += __shfl_xor(m1, m);
        mb += __shfl_xor(mb, m);
      }
      m0 *= (1.f / DD);
      m1 *= (1.f / DD);
      mb *= (1.f / DD);
      float a0 = w0 - m0, a1 = w1 - m1, ab = bb - mb;
      float grt = gr[t];
      float4v kt;
      kt[0] = grt * a0;
      kt[1] = grt * a1;
      kt[2] = grt * ab;
      kt[3] = ber[t];
      KT[t] = kt;
      // GB packs the sigmoid-folded LN affine: {-log2e*gg, -log2e*beg}
      float2v gb;
      gb[0] = -LOG2E * gg[t];
      gb[1] = -LOG2E * beg[t];
      GB[t] = gb;
      float e00 = a0 * a0, e11 = a1 * a1, ebb = ab * ab;
      float e01 = a0 * a1, e0b = a0 * ab, e1b = a1 * ab;
      for (int m = 1; m < 64; m <<= 1) {
        e00 += __shfl_xor(e00, m);
        e11 += __shfl_xor(e11, m);
        ebb += __shfl_xor(ebb, m);
        e01 += __shfl_xor(e01, m);
        e0b += __shfl_xor(e0b, m);
        e1b += __shfl_xor(e1b, m);
      }
      if (t == 0) {
        evec[0] = e00 * (1.f / DD);
        evec[1] = e11 * (1.f / DD);
        evec[2] = ebb * (1.f / DD);
        evec[3] = e01 * (1.f / DD);
        evec[4] = e0b * (1.f / DD);
        evec[5] = e1b * (1.f / DD);
      }
    }
    return;
  }

  // Row GEMV, K-split: wave w accumulates k in [16w, 16w+16).
  __shared__ float redA[4][DD];
  __shared__ float redB[4][DD];
  const int w = tid >> 6;
  const int lane = tid & 63;  // == d
  const int i = bid;
  float hv = hidden[i * DD + lane];
  float a = 0.f, b = 0.f;
#pragma unroll
  for (int j = 0; j < 16; ++j) {
    int k = w * 16 + j;
    float hk = __shfl(hv, k);
    a = fmaf(hk, Wg[(DD + k) * DD + lane], a);
    b = fmaf(hk, Wg[(2 * DD + k) * DD + lane], b);
  }
  redA[w][lane] = a;
  redB[w][lane] = b;
  __syncthreads();
  if (tid < 64) {
    float aa = bg[lane] + redA[0][lane] + redA[1][lane] + redA[2][lane] +
               redA[3][lane];
    float bb = redB[0][lane] + redB[1][lane] + redB[2][lane] + redB[3][lane];
    A_pre[i * DD + lane] = aa;
    float2v bh2;
    bh2[0] = bb;
    bh2[1] = hv;
    BH[i * DD + lane] = bh2;
  }
}

// ---------------------------------------------------------------------------
// Monolith: one block per row i (768 x 512 = 8 waves). Constant loads at
// entry (latency overlaps compaction); compaction writes Lst + corr to LDS
// (+16 pad); 16-pair tiles with pinned-early BH gathers, shuffle R-build,
// MFMA, epilogue; in-block close.
// ---------------------------------------------------------------------------
__global__ __launch_bounds__(512, 4) void gat_kernel(
    const int* __restrict__ nei, const float2v* __restrict__ corr2,
    const float* __restrict__ A_pre, const float2v* __restrict__ BH,
    const float4v* __restrict__ KT, const float2v* __restrict__ GB,
    const float* __restrict__ evec, const unsigned short* __restrict__ WgT,
    const float* __restrict__ hidden, const float* __restrict__ cn,
    const float* __restrict__ bea, const float* __restrict__ Ww,
    const float* __restrict__ bw, const float* __restrict__ gw,
    const float* __restrict__ bew, float* __restrict__ out) {
  __shared__ unsigned short Lst[NN + 16];
  __shared__ float2v CcL[NN + 16];
  __shared__ __align__(16) unsigned short Rt[8][16 * 72];  // per-wave slice
  __shared__ float red[8][DD];
  __shared__ int cLds;

  const int i = blockIdx.x;
  const int tid = threadIdx.x;
  const int wid = tid >> 6;
  const int lane = tid & 63;
  const int quad = lane >> 4;
  const int nl = lane & 15;

  // --- Constant loads issued FIRST: ~14 global loads whose latency overlaps
  // the compaction phase below (they have no dependency on it).
  const float e00 = evec[0], e11 = evec[1], ebb = evec[2];
  const float e01 = evec[3], e0b = evec[4], e1b = evec[5];
  const float4v kt = KT[lane];  // k = lane: {gr*w0h, gr*w1h, gr*bh, ber}
  short8 Bf[2][4];
#pragma unroll
  for (int ks = 0; ks < 2; ++ks)
#pragma unroll
    for (int nt = 0; nt < 4; ++nt)
      __builtin_memcpy(&Bf[ks][nt],
                       &WgT[(nt * 16 + nl) * DD + ks * 32 + quad * 8], 16);
  float ngg[4], nbeg[4], pre4[4];
#pragma unroll
  for (int nt = 0; nt < 4; ++nt) {
    int d = nt * 16 + nl;
    float2v gb = GB[d];
    ngg[nt] = gb[0];   // -log2e * gg
    nbeg[nt] = gb[1];  // -log2e * beg
    pre4[nt] = A_pre[i * DD + d];
  }

  if (tid == 0) cLds = 0;
  __syncthreads();
  {
    int jj = tid;  // 0..511, always < NN
    if (nei[i * NN + jj] > 0) {
      int idx = atomicAdd(&cLds, 1);
      Lst[idx] = (unsigned short)jj;
      CcL[idx] = corr2[i * NN + jj];
    }
    jj = tid + 512;  // 512..1023: guard against running past row i
    if (jj < NN && nei[i * NN + jj] > 0) {
      int idx = atomicAdd(&cLds, 1);
      Lst[idx] = (unsigned short)jj;
      CcL[idx] = corr2[i * NN + jj];
    }
  }
  __syncthreads();
  const int cnt = cLds;
  if (cnt > 0 && tid < 16) {  // tail pad: no clamps in the tile loop
    Lst[cnt + tid] = Lst[0];
    CcL[cnt + tid] = CcL[0];
  }

  float accT[4] = {0.f, 0.f, 0.f, 0.f};
  __syncthreads();  // pad visible to all waves

  // Tile-0 pair ids + corr, then software-pipelined via next-tile prefetch.
  ushort4v l4 = {0, 0, 0, 0};
  float2v cc = {0.f, 0.f};
  if (wid * 16 < cnt) {
    __builtin_memcpy(&l4, &Lst[wid * 16 + quad * 4], 8);
    cc = CcL[wid * 16 + nl];
  }

  for (int base = wid * 16; base < cnt; base += 128) {
    // Prefetch next tile's l4/cc (LDS) off the critical path.
    const int nb = base + 128;
    ushort4v l4n = l4;
    float2v ccn = cc;
    if (nb < cnt) {
      __builtin_memcpy(&l4n, &Lst[nb + quad * 4], 8);
      ccn = CcL[nb + nl];
    }

    // All 16 BH gathers issued early + pinned (latency under R-build+MFMA).
    float2v bh[4][4];
#pragma unroll
    for (int rr = 0; rr < 4; ++rr) {
      const int jpr = (int)l4[rr];
#pragma unroll
      for (int nt = 0; nt < 4; ++nt) bh[rr][nt] = BH[jpr * DD + nt * 16 + nl];
    }
    asm volatile("" ::: "memory");  // pin: loads above may not sink below

    // Per-pair analytic LN scale (pair = nl, replicated across quads).
    float var = cc[0] * cc[0] * e00 + cc[1] * cc[1] * e11 + ebb +
                2.f * (cc[0] * cc[1] * e01 + cc[0] * e0b + cc[1] * e1b);
    float iv = __builtin_amdgcn_rsqf(var + EPSF);

    // R build: lane==k writes 16 rows; pair q broadcast via shfl. Same-wave
    // DS ops execute in order; compiler orders the reads below via aliasing.
#pragma unroll
    for (int q = 0; q < 16; ++q) {
      float sc0 = __shfl(cc[0], q);
      float sc1 = __shfl(cc[1], q);
      float siv = __shfl(iv, q);
      float s3 = fmaf(sc0, kt[0], fmaf(sc1, kt[1], kt[2]));
      float r = fmaxf(0.f, fmaf(siv, s3, kt[3]));
      Rt[wid][q * 72 + lane] = f2bf(r);
    }

    short8 a0, a1;
    __builtin_memcpy(&a0, &Rt[wid][nl * 72 + quad * 8], 16);
    __builtin_memcpy(&a1, &Rt[wid][nl * 72 + 32 + quad * 8], 16);
    float4v acc[4];
#pragma unroll
    for (int nt = 0; nt < 4; ++nt) {
      float4v z = {0.f, 0.f, 0.f, 0.f};
      z = __builtin_amdgcn_mfma_f32_16x16x32_bf16(a0, Bf[0][nt], z, 0, 0, 0);
      z = __builtin_amdgcn_mfma_f32_16x16x32_bf16(a1, Bf[1][nt], z, 0, 0, 0);
      acc[nt] = z;
    }

    // Epilogue: per-C-row LN + sigmoid gate + accumulate gate*h[j].
#pragma unroll
    for (int rr = 0; rr < 4; ++rr) {
      const float pvr = (base + quad * 4 + rr < cnt) ? 1.f : 0.f;
      float y0 = acc[0][rr] + pre4[0] + bh[rr][0][0];
      float y1 = acc[1][rr] + pre4[1] + bh[rr][1][0];
      float y2 = acc[2][rr] + pre4[2] + bh[rr][2][0];
      float y3 = acc[3][rr] + pre4[3] + bh[rr][3][0];
      float s = y0 + y1 + y2 + y3;
      float qq = y0 * y0 + y1 * y1 + y2 * y2 + y3 * y3;
#pragma unroll
      for (int m = 1; m < 16; m <<= 1) {
        s += __shfl_xor(s, m);
        qq += __shfl_xor(qq, m);
      }
      float u = s * (1.f / DD);
      float vv = qq * (1.f / DD) - u * u;
      float inv = __builtin_amdgcn_rsqf(vv + EPSF);
      float g0 = __builtin_amdgcn_exp2f(fmaf(ngg[0] * (y0 - u), inv, nbeg[0]));
      float g1 = __builtin_amdgcn_exp2f(fmaf(ngg[1] * (y1 - u), inv, nbeg[1]));
      float g2 = __builtin_amdgcn_exp2f(fmaf(ngg[2] * (y2 - u), inv, nbeg[2]));
      float g3 = __builtin_amdgcn_exp2f(fmaf(ngg[3] * (y3 - u), inv, nbeg[3]));
      accT[0] =
          fmaf(__builtin_amdgcn_rcpf(1.f + g0) * pvr, bh[rr][0][1], accT[0]);
      accT[1] =
          fmaf(__builtin_amdgcn_rcpf(1.f + g1) * pvr, bh[rr][1][1], accT[1]);
      accT[2] =
          fmaf(__builtin_amdgcn_rcpf(1.f + g2) * pvr, bh[rr][2][1], accT[2]);
      accT[3] =
          fmaf(__builtin_amdgcn_rcpf(1.f + g3) * pvr, bh[rr][3][1], accT[3]);
    }

    l4 = l4n;
    cc = ccn;
  }

  // Per-wave partials -> LDS (all 8 waves reach here).
#pragma unroll
  for (int nt = 0; nt < 4; ++nt) {
    accT[nt] += __shfl_xor(accT[nt], 16);
    accT[nt] += __shfl_xor(accT[nt], 32);
  }
  if (lane < 16) {
#pragma unroll
    for (int nt = 0; nt < 4; ++nt) red[wid][nt * 16 + nl] = accT[nt];
  }
  __syncthreads();

  if (tid < 64) {  // wave 0 closes the row
    const int d = tid;
    float hs = 0.f;
#pragma unroll
    for (int w = 0; w < 8; ++w) hs += red[w][d];
    float tta = fmaxf(bea[0], 0.f);
    float wgt = (tta > 0.f && cnt > 0) ? __builtin_amdgcn_rcpf((float)cnt)
                                       : (1.f / (float)NN);
    hs *= wgt;  // H_sum[i][d]

    float dotv = bw[d];
#pragma unroll 8
    for (int k = 0; k < DD; ++k) {
      float hk = __shfl(hs, k);
      dotv = fmaf(hk, Ww[k * DD + d], dotv);
    }
    float s = dotv, qq = dotv * dotv;
#pragma unroll
    for (int m = 1; m < 64; m <<= 1) {
      s += __shfl_xor(s, m);
      qq += __shfl_xor(qq, m);
    }
    float u = s * (1.f / DD);
    float var2 = qq * (1.f / DD) - u * u;
    float inv = __builtin_amdgcn_rsqf(var2 + EPSF);
    float val = fmaxf(0.f, fmaf(gw[d], (dotv - u) * inv, bew[d]));
    float Cv = val + cn[i * DD + d];
    out[i * DD + d] = hidden[i * DD + d] + fast_tanh(Cv);
    out[NN * DD + i * DD + d] = Cv;
  }
}

extern "C" void kernel_launch(void* const* d_in, const int* in_sizes, int n_in,
                              void* d_out, int out_size, void* d_ws,
                              size_t ws_size, hipStream_t stream) {
  const float* corr = (const float*)d_in[0];
  const int* nei = (const int*)d_in[1];
  // d_in[2] nei_num: unused by the reference math
  const float* hidden = (const float*)d_in[3];
  const float* cn = (const float*)d_in[4];
  const float* Wr = (const float*)d_in[5];
  const float* br = (const float*)d_in[6];
  const float* gr = (const float*)d_in[7];
  const float* ber = (const float*)d_in[8];
  const float* Wg = (const float*)d_in[9];
  const float* bg = (const float*)d_in[10];
  const float* gg = (const float*)d_in[11];
  const float* beg = (const float*)d_in[12];
  // d_in[13..15] W_a/b_a/g_a: cancel analytically
  const float* bea = (const float*)d_in[16];
  const float* Ww = (const float*)d_in[17];
  const float* bw = (const float*)d_in[18];
  const float* gw = (const float*)d_in[19];
  const float* bew = (const float*)d_in[20];
  float* out = (float*)d_out;

  float* ws = (float*)d_ws;
  float* A_pre = ws;                                     // 49152 floats
  float2v* BH = (float2v*)(ws + 49152);                  // 98304 floats
  float4v* KT = (float4v*)(ws + 147456);                 // 256 floats
  float2v* GB = (float2v*)(ws + 147712);                 // 128 floats
  float* evec = ws + 147840;                             // 16 floats
  unsigned short* WgT = (unsigned short*)(ws + 147856);  // 4096 shorts

  prep_kernel<<<NN + 1, 256, 0, stream>>>(hidden, Wg, bg, Wr, br, gr, ber, gg,
                                          beg, A_pre, BH, KT, GB, evec, WgT);
  gat_kernel<<<NN, 512, 0, stream>>>((const int*)nei, (const float2v*)corr,
                                     A_pre, BH, KT, GB, evec, WgT, hidden, cn,
                                     bea, Ww, bw, gw, bew, out);
}

// Round 13
// 127.737 us; speedup vs baseline: 1.0379x; 1.0379x over previous
//
#include <hip/hip_runtime.h>

// GATraj fused kernels for MI355X (gfx950) — round 13.
//
// Math simplifications (verified passing rounds 1-12):
//  * LN over the size-1 W_a channel == be_a exactly -> Pos uniform 1/cnt_i
//    (or 1/768 if relu(be_a)==0 or cnt==0). W_a/b_a/g_a unused.
//  * tmp @ W_g splits; h_i/h_j parts precomputed (A_pre, BH).
//  * r-LayerNorm analytic via 6 moments of centered W_r (KT table).
//
// Round-13 (r12 post-mortem: entry-hoisted constants living across the
// compaction barriers + loop-carried l4n/ccn tipped VGPRs past the 128 cap
// -> scratch spill, WRITE 0.4->9.4MB, gat +4us): gat reverted EXACTLY to
// r11's proven best (<39.6us, no spill): constants after compaction, no
// software pipeline, pinned BH gathers, no fence. Keep r12's K-split prep
// (768 blocks x 4-wave reduce).

#define NN 768
#define DD 64
#define EPSF 1e-5f
#define LOG2E 1.44269504f

typedef __attribute__((ext_vector_type(8))) short short8;
typedef __attribute__((ext_vector_type(4))) float float4v;
typedef __attribute__((ext_vector_type(2))) float float2v;
typedef __attribute__((ext_vector_type(4))) unsigned short ushort4v;

__device__ __forceinline__ unsigned short f2bf(float f) {
  unsigned int u = __float_as_uint(f);
  u += 0x7fffu + ((u >> 16) & 1u);  // round-to-nearest-even
  return (unsigned short)(u >> 16);
}

__device__ __forceinline__ float fast_tanh(float x) {
  float e = __builtin_amdgcn_exp2f(fminf(x, 20.f) * (2.f * LOG2E));
  return (e - 1.f) * __builtin_amdgcn_rcpf(e + 1.f);
}

// ---------------------------------------------------------------------------
// Prep kernel, grid = 769 blocks x 256 threads:
//   bid < 768  : row bid's A_pre/BH GEMV, K-split across 4 waves + LDS reduce
//   bid == 768 : transposed bf16 Wg_lo pack + W_r moments -> KT/GB/evec
// ---------------------------------------------------------------------------
__global__ __launch_bounds__(256) void prep_kernel(
    const float* __restrict__ hidden, const float* __restrict__ Wg,
    const float* __restrict__ bg, const float* __restrict__ Wr,
    const float* __restrict__ br, const float* __restrict__ gr,
    const float* __restrict__ ber, const float* __restrict__ gg,
    const float* __restrict__ beg, float* __restrict__ A_pre,
    float2v* __restrict__ BH, float4v* __restrict__ KT,
    float2v* __restrict__ GB, float* __restrict__ evec,
    unsigned short* __restrict__ WgT) {
  const int bid = blockIdx.x;
  const int tid = threadIdx.x;

  if (bid == NN) {
    for (int idx = tid; idx < DD * DD; idx += 256) {
      int n = idx >> 6, k = idx & 63;
      WgT[idx] = f2bf(Wg[k * DD + n]);
    }
    if (tid < 64) {  // wave 0: W_r moments, KT, GB, evec
      int t = tid;
      float w0 = Wr[t], w1 = Wr[DD + t], bb = br[t];
      float m0 = w0, m1 = w1, mb = bb;
      for (int m = 1; m < 64; m <<= 1) {
        m0 += __shfl_xor(m0, m);
        m1 += __shfl_xor(m1, m);
        mb += __shfl_xor(mb, m);
      }
      m0 *= (1.f / DD);
      m1 *= (1.f / DD);
      mb *= (1.f / DD);
      float a0 = w0 - m0, a1 = w1 - m1, ab = bb - mb;
      float grt = gr[t];
      float4v kt;
      kt[0] = grt * a0;
      kt[1] = grt * a1;
      kt[2] = grt * ab;
      kt[3] = ber[t];
      KT[t] = kt;
      // GB packs the sigmoid-folded LN affine: {-log2e*gg, -log2e*beg}
      float2v gb;
      gb[0] = -LOG2E * gg[t];
      gb[1] = -LOG2E * beg[t];
      GB[t] = gb;
      float e00 = a0 * a0, e11 = a1 * a1, ebb = ab * ab;
      float e01 = a0 * a1, e0b = a0 * ab, e1b = a1 * ab;
      for (int m = 1; m < 64; m <<= 1) {
        e00 += __shfl_xor(e00, m);
        e11 += __shfl_xor(e11, m);
        ebb += __shfl_xor(ebb, m);
        e01 += __shfl_xor(e01, m);
        e0b += __shfl_xor(e0b, m);
        e1b += __shfl_xor(e1b, m);
      }
      if (t == 0) {
        evec[0] = e00 * (1.f / DD);
        evec[1] = e11 * (1.f / DD);
        evec[2] = ebb * (1.f / DD);
        evec[3] = e01 * (1.f / DD);
        evec[4] = e0b * (1.f / DD);
        evec[5] = e1b * (1.f / DD);
      }
    }
    return;
  }

  // Row GEMV, K-split: wave w accumulates k in [16w, 16w+16).
  __shared__ float redA[4][DD];
  __shared__ float redB[4][DD];
  const int w = tid >> 6;
  const int lane = tid & 63;  // == d
  const int i = bid;
  float hv = hidden[i * DD + lane];
  float a = 0.f, b = 0.f;
#pragma unroll
  for (int j = 0; j < 16; ++j) {
    int k = w * 16 + j;
    float hk = __shfl(hv, k);
    a = fmaf(hk, Wg[(DD + k) * DD + lane], a);
    b = fmaf(hk, Wg[(2 * DD + k) * DD + lane], b);
  }
  redA[w][lane] = a;
  redB[w][lane] = b;
  __syncthreads();
  if (tid < 64) {
    float aa = bg[lane] + redA[0][lane] + redA[1][lane] + redA[2][lane] +
               redA[3][lane];
    float bb = redB[0][lane] + redB[1][lane] + redB[2][lane] + redB[3][lane];
    A_pre[i * DD + lane] = aa;
    float2v bh2;
    bh2[0] = bb;
    bh2[1] = hv;
    BH[i * DD + lane] = bh2;
  }
}

// ---------------------------------------------------------------------------
// Monolith (r11-exact): one block per row i (768 x 512 = 8 waves).
// Compaction writes Lst + corr to LDS (+16 pad); 16-pair tiles with
// pinned-early BH gathers, shuffle R-build, MFMA, epilogue; in-block close.
// ---------------------------------------------------------------------------
__global__ __launch_bounds__(512, 4) void gat_kernel(
    const int* __restrict__ nei, const float2v* __restrict__ corr2,
    const float* __restrict__ A_pre, const float2v* __restrict__ BH,
    const float4v* __restrict__ KT, const float2v* __restrict__ GB,
    const float* __restrict__ evec, const unsigned short* __restrict__ WgT,
    const float* __restrict__ hidden, const float* __restrict__ cn,
    const float* __restrict__ bea, const float* __restrict__ Ww,
    const float* __restrict__ bw, const float* __restrict__ gw,
    const float* __restrict__ bew, float* __restrict__ out) {
  __shared__ unsigned short Lst[NN + 16];
  __shared__ float2v CcL[NN + 16];
  __shared__ __align__(16) unsigned short Rt[8][16 * 72];  // per-wave slice
  __shared__ float red[8][DD];
  __shared__ int cLds;

  const int i = blockIdx.x;
  const int tid = threadIdx.x;
  const int wid = tid >> 6;
  const int lane = tid & 63;
  const int quad = lane >> 4;
  const int nl = lane & 15;

  if (tid == 0) cLds = 0;
  __syncthreads();
  {
    int jj = tid;  // 0..511, always < NN
    if (nei[i * NN + jj] > 0) {
      int idx = atomicAdd(&cLds, 1);
      Lst[idx] = (unsigned short)jj;
      CcL[idx] = corr2[i * NN + jj];
    }
    jj = tid + 512;  // 512..1023: guard against running past row i
    if (jj < NN && nei[i * NN + jj] > 0) {
      int idx = atomicAdd(&cLds, 1);
      Lst[idx] = (unsigned short)jj;
      CcL[idx] = corr2[i * NN + jj];
    }
  }
  __syncthreads();
  const int cnt = cLds;
  if (cnt > 0 && tid < 16) {  // tail pad: no clamps in the tile loop
    Lst[cnt + tid] = Lst[0];
    CcL[cnt + tid] = CcL[0];
  }

  // Uniform constants (loaded AFTER compaction: live ranges must not span
  // the barriers above — r12 proved that spills).
  const float e00 = evec[0], e11 = evec[1], ebb = evec[2];
  const float e01 = evec[3], e0b = evec[4], e1b = evec[5];
  const float4v kt = KT[lane];  // k = lane: {gr*w0h, gr*w1h, gr*bh, ber}

  // B fragments of Wg_lo (16B contiguous from transposed pack).
  short8 Bf[2][4];
#pragma unroll
  for (int ks = 0; ks < 2; ++ks)
#pragma unroll
    for (int nt = 0; nt < 4; ++nt)
      __builtin_memcpy(&Bf[ks][nt],
                       &WgT[(nt * 16 + nl) * DD + ks * 32 + quad * 8], 16);

  float ngg[4], nbeg[4], pre4[4];
#pragma unroll
  for (int nt = 0; nt < 4; ++nt) {
    int d = nt * 16 + nl;
    float2v gb = GB[d];
    ngg[nt] = gb[0];   // -log2e * gg
    nbeg[nt] = gb[1];  // -log2e * beg
    pre4[nt] = A_pre[i * DD + d];
  }

  float accT[4] = {0.f, 0.f, 0.f, 0.f};
  __syncthreads();  // pad visible to all waves

  for (int base = wid * 16; base < cnt; base += 128) {
    // --- Issue phase: pair ids, corr, and ALL 16 BH gathers, pinned early so
    // their latency hides under the R-build + MFMAs below.
    ushort4v l4;
    __builtin_memcpy(&l4, &Lst[base + quad * 4], 8);
    float2v cc = CcL[base + nl];
    float2v bh[4][4];
#pragma unroll
    for (int rr = 0; rr < 4; ++rr) {
      const int jpr = (int)l4[rr];
#pragma unroll
      for (int nt = 0; nt < 4; ++nt) bh[rr][nt] = BH[jpr * DD + nt * 16 + nl];
    }
    asm volatile("" ::: "memory");  // pin: loads above may not sink below

    // Per-pair analytic LN scale (pair = nl, replicated across quads).
    float var = cc[0] * cc[0] * e00 + cc[1] * cc[1] * e11 + ebb +
                2.f * (cc[0] * cc[1] * e01 + cc[0] * e0b + cc[1] * e1b);
    float iv = __builtin_amdgcn_rsqf(var + EPSF);

    // R build: lane==k writes 16 rows; pair q broadcast via shfl. Same-wave
    // DS ops execute in order; compiler orders the reads below via aliasing.
#pragma unroll
    for (int q = 0; q < 16; ++q) {
      float sc0 = __shfl(cc[0], q);
      float sc1 = __shfl(cc[1], q);
      float siv = __shfl(iv, q);
      float s3 = fmaf(sc0, kt[0], fmaf(sc1, kt[1], kt[2]));
      float r = fmaxf(0.f, fmaf(siv, s3, kt[3]));
      Rt[wid][q * 72 + lane] = f2bf(r);
    }

    short8 a0, a1;
    __builtin_memcpy(&a0, &Rt[wid][nl * 72 + quad * 8], 16);
    __builtin_memcpy(&a1, &Rt[wid][nl * 72 + 32 + quad * 8], 16);
    float4v acc[4];
#pragma unroll
    for (int nt = 0; nt < 4; ++nt) {
      float4v z = {0.f, 0.f, 0.f, 0.f};
      z = __builtin_amdgcn_mfma_f32_16x16x32_bf16(a0, Bf[0][nt], z, 0, 0, 0);
      z = __builtin_amdgcn_mfma_f32_16x16x32_bf16(a1, Bf[1][nt], z, 0, 0, 0);
      acc[nt] = z;
    }

    // Epilogue: per-C-row LN + sigmoid gate + accumulate gate*h[j].
#pragma unroll
    for (int rr = 0; rr < 4; ++rr) {
      const float pvr = (base + quad * 4 + rr < cnt) ? 1.f : 0.f;
      float y0 = acc[0][rr] + pre4[0] + bh[rr][0][0];
      float y1 = acc[1][rr] + pre4[1] + bh[rr][1][0];
      float y2 = acc[2][rr] + pre4[2] + bh[rr][2][0];
      float y3 = acc[3][rr] + pre4[3] + bh[rr][3][0];
      float s = y0 + y1 + y2 + y3;
      float qq = y0 * y0 + y1 * y1 + y2 * y2 + y3 * y3;
#pragma unroll
      for (int m = 1; m < 16; m <<= 1) {
        s += __shfl_xor(s, m);
        qq += __shfl_xor(qq, m);
      }
      float u = s * (1.f / DD);
      float vv = qq * (1.f / DD) - u * u;
      float inv = __builtin_amdgcn_rsqf(vv + EPSF);
      float g0 = __builtin_amdgcn_exp2f(fmaf(ngg[0] * (y0 - u), inv, nbeg[0]));
      float g1 = __builtin_amdgcn_exp2f(fmaf(ngg[1] * (y1 - u), inv, nbeg[1]));
      float g2 = __builtin_amdgcn_exp2f(fmaf(ngg[2] * (y2 - u), inv, nbeg[2]));
      float g3 = __builtin_amdgcn_exp2f(fmaf(ngg[3] * (y3 - u), inv, nbeg[3]));
      accT[0] =
          fmaf(__builtin_amdgcn_rcpf(1.f + g0) * pvr, bh[rr][0][1], accT[0]);
      accT[1] =
          fmaf(__builtin_amdgcn_rcpf(1.f + g1) * pvr, bh[rr][1][1], accT[1]);
      accT[2] =
          fmaf(__builtin_amdgcn_rcpf(1.f + g2) * pvr, bh[rr][2][1], accT[2]);
      accT[3] =
          fmaf(__builtin_amdgcn_rcpf(1.f + g3) * pvr, bh[rr][3][1], accT[3]);
    }
  }

  // Per-wave partials -> LDS (all 8 waves reach here).
#pragma unroll
  for (int nt = 0; nt < 4; ++nt) {
    accT[nt] += __shfl_xor(accT[nt], 16);
    accT[nt] += __shfl_xor(accT[nt], 32);
  }
  if (lane < 16) {
#pragma unroll
    for (int nt = 0; nt < 4; ++nt) red[wid][nt * 16 + nl] = accT[nt];
  }
  __syncthreads();

  if (tid < 64) {  // wave 0 closes the row
    const int d = tid;
    float hs = 0.f;
#pragma unroll
    for (int w = 0; w < 8; ++w) hs += red[w][d];
    float tta = fmaxf(bea[0], 0.f);
    float wgt = (tta > 0.f && cnt > 0) ? __builtin_amdgcn_rcpf((float)cnt)
                                       : (1.f / (float)NN);
    hs *= wgt;  // H_sum[i][d]

    float dotv = bw[d];
#pragma unroll 8
    for (int k = 0; k < DD; ++k) {
      float hk = __shfl(hs, k);
      dotv = fmaf(hk, Ww[k * DD + d], dotv);
    }
    float s = dotv, qq = dotv * dotv;
#pragma unroll
    for (int m = 1; m < 64; m <<= 1) {
      s += __shfl_xor(s, m);
      qq += __shfl_xor(qq, m);
    }
    float u = s * (1.f / DD);
    float var2 = qq * (1.f / DD) - u * u;
    float inv = __builtin_amdgcn_rsqf(var2 + EPSF);
    float val = fmaxf(0.f, fmaf(gw[d], (dotv - u) * inv, bew[d]));
    float Cv = val + cn[i * DD + d];
    out[i * DD + d] = hidden[i * DD + d] + fast_tanh(Cv);
    out[NN * DD + i * DD + d] = Cv;
  }
}

extern "C" void kernel_launch(void* const* d_in, const int* in_sizes, int n_in,
                              void* d_out, int out_size, void* d_ws,
                              size_t ws_size, hipStream_t stream) {
  const float* corr = (const float*)d_in[0];
  const int* nei = (const int*)d_in[1];
  // d_in[2] nei_num: unused by the reference math
  const float* hidden = (const float*)d_in[3];
  const float* cn = (const float*)d_in[4];
  const float* Wr = (const float*)d_in[5];
  const float* br = (const float*)d_in[6];
  const float* gr = (const float*)d_in[7];
  const float* ber = (const float*)d_in[8];
  const float* Wg = (const float*)d_in[9];
  const float* bg = (const float*)d_in[10];
  const float* gg = (const float*)d_in[11];
  const float* beg = (const float*)d_in[12];
  // d_in[13..15] W_a/b_a/g_a: cancel analytically
  const float* bea = (const float*)d_in[16];
  const float* Ww = (const float*)d_in[17];
  const float* bw = (const float*)d_in[18];
  const float* gw = (const float*)d_in[19];
  const float* bew = (const float*)d_in[20];
  float* out = (float*)d_out;

  float* ws = (float*)d_ws;
  float* A_pre = ws;                                     // 49152 floats
  float2v* BH = (float2v*)(ws + 49152);                  // 98304 floats
  float4v* KT = (float4v*)(ws + 147456);                 // 256 floats
  float2v* GB = (float2v*)(ws + 147712);                 // 128 floats
  float* evec = ws + 147840;                             // 16 floats
  unsigned short* WgT = (unsigned short*)(ws + 147856);  // 4096 shorts

  prep_kernel<<<NN + 1, 256, 0, stream>>>(hidden, Wg, bg, Wr, br, gr, ber, gg,
                                          beg, A_pre, BH, KT, GB, evec, WgT);
  gat_kernel<<<NN, 512, 0, stream>>>((const int*)nei, (const float2v*)corr,
                                     A_pre, BH, KT, GB, evec, WgT, hidden, cn,
                                     bea, Ww, bw, gw, bew, out);
}

// Round 14
// 123.938 us; speedup vs baseline: 1.0697x; 1.0307x over previous
//
#include <hip/hip_runtime.h>

// GATraj fused kernels for MI355X (gfx950) — round 14.
//
// Math simplifications (verified passing rounds 1-13):
//  * LN over the size-1 W_a channel == be_a exactly -> Pos uniform 1/cnt_i
//    (or 1/768 if relu(be_a)==0 or cnt==0). W_a/b_a/g_a unused.
//  * tmp @ W_g splits; h_i/h_j parts precomputed (A_pre, BH).
//  * r-LayerNorm analytic via 6 moments of centered W_r (KT table);
//    r = relu(d0*kt0 + d1*kt1 + iv*kt2 + kt3) with {d0,d1,iv} PER-PAIR.
//
// Round-14 (r13 = 127.7us, top-5 all harness poison-fill; gat's remaining
// stall is the per-tile DS chain): {d0,d1,iv} moved to COMPACTION time
// (CcI float4 in LDS) -> R-build per pair = 1 broadcast ds_read_b128 +
// 3 fma + cvt + write. Removes 48 shuffles + var/rsq per tile. Build reads
// grouped 4x4 with asm barriers to cap in-flight LDS regs (r9/r12 spill
// lesson). LDS 28.7->34.9KB, still 4 blocks/CU (wave-capped).

#define NN 768
#define DD 64
#define EPSF 1e-5f
#define LOG2E 1.44269504f

typedef __attribute__((ext_vector_type(8))) short short8;
typedef __attribute__((ext_vector_type(4))) float float4v;
typedef __attribute__((ext_vector_type(2))) float float2v;
typedef __attribute__((ext_vector_type(4))) unsigned short ushort4v;

__device__ __forceinline__ unsigned short f2bf(float f) {
  unsigned int u = __float_as_uint(f);
  u += 0x7fffu + ((u >> 16) & 1u);  // round-to-nearest-even
  return (unsigned short)(u >> 16);
}

__device__ __forceinline__ float fast_tanh(float x) {
  float e = __builtin_amdgcn_exp2f(fminf(x, 20.f) * (2.f * LOG2E));
  return (e - 1.f) * __builtin_amdgcn_rcpf(e + 1.f);
}

// ---------------------------------------------------------------------------
// Prep kernel, grid = 769 blocks x 256 threads (r13's version):
//   bid < 768  : row bid's A_pre/BH GEMV, K-split across 4 waves + LDS reduce
//   bid == 768 : transposed bf16 Wg_lo pack + W_r moments -> KT/GB/evec
// ---------------------------------------------------------------------------
__global__ __launch_bounds__(256) void prep_kernel(
    const float* __restrict__ hidden, const float* __restrict__ Wg,
    const float* __restrict__ bg, const float* __restrict__ Wr,
    const float* __restrict__ br, const float* __restrict__ gr,
    const float* __restrict__ ber, const float* __restrict__ gg,
    const float* __restrict__ beg, float* __restrict__ A_pre,
    float2v* __restrict__ BH, float4v* __restrict__ KT,
    float2v* __restrict__ GB, float* __restrict__ evec,
    unsigned short* __restrict__ WgT) {
  const int bid = blockIdx.x;
  const int tid = threadIdx.x;

  if (bid == NN) {
    for (int idx = tid; idx < DD * DD; idx += 256) {
      int n = idx >> 6, k = idx & 63;
      WgT[idx] = f2bf(Wg[k * DD + n]);
    }
    if (tid < 64) {  // wave 0: W_r moments, KT, GB, evec
      int t = tid;
      float w0 = Wr[t], w1 = Wr[DD + t], bb = br[t];
      float m0 = w0, m1 = w1, mb = bb;
      for (int m = 1; m < 64; m <<= 1) {
        m0 += __shfl_xor(m0, m);
        m1 += __shfl_xor(m1, m);
        mb += __shfl_xor(mb, m);
      }
      m0 *= (1.f / DD);
      m1 *= (1.f / DD);
      mb *= (1.f / DD);
      float a0 = w0 - m0, a1 = w1 - m1, ab = bb - mb;
      float grt = gr[t];
      float4v kt;
      kt[0] = grt * a0;
      kt[1] = grt * a1;
      kt[2] = grt * ab;
      kt[3] = ber[t];
      KT[t] = kt;
      // GB packs the sigmoid-folded LN affine: {-log2e*gg, -log2e*beg}
      float2v gb;
      gb[0] = -LOG2E * gg[t];
      gb[1] = -LOG2E * beg[t];
      GB[t] = gb;
      float e00 = a0 * a0, e11 = a1 * a1, ebb = ab * ab;
      float e01 = a0 * a1, e0b = a0 * ab, e1b = a1 * ab;
      for (int m = 1; m < 64; m <<= 1) {
        e00 += __shfl_xor(e00, m);
        e11 += __shfl_xor(e11, m);
        ebb += __shfl_xor(ebb, m);
        e01 += __shfl_xor(e01, m);
        e0b += __shfl_xor(e0b, m);
        e1b += __shfl_xor(e1b, m);
      }
      if (t == 0) {
        evec[0] = e00 * (1.f / DD);
        evec[1] = e11 * (1.f / DD);
        evec[2] = ebb * (1.f / DD);
        evec[3] = e01 * (1.f / DD);
        evec[4] = e0b * (1.f / DD);
        evec[5] = e1b * (1.f / DD);
      }
    }
    return;
  }

  // Row GEMV, K-split: wave w accumulates k in [16w, 16w+16).
  __shared__ float redA[4][DD];
  __shared__ float redB[4][DD];
  const int w = tid >> 6;
  const int lane = tid & 63;  // == d
  const int i = bid;
  float hv = hidden[i * DD + lane];
  float a = 0.f, b = 0.f;
#pragma unroll
  for (int j = 0; j < 16; ++j) {
    int k = w * 16 + j;
    float hk = __shfl(hv, k);
    a = fmaf(hk, Wg[(DD + k) * DD + lane], a);
    b = fmaf(hk, Wg[(2 * DD + k) * DD + lane], b);
  }
  redA[w][lane] = a;
  redB[w][lane] = b;
  __syncthreads();
  if (tid < 64) {
    float aa = bg[lane] + redA[0][lane] + redA[1][lane] + redA[2][lane] +
               redA[3][lane];
    float bb = redB[0][lane] + redB[1][lane] + redB[2][lane] + redB[3][lane];
    A_pre[i * DD + lane] = aa;
    float2v bh2;
    bh2[0] = bb;
    bh2[1] = hv;
    BH[i * DD + lane] = bh2;
  }
}

// ---------------------------------------------------------------------------
// Monolith: one block per row i (768 x 512 = 8 waves). Compaction computes
// per-pair {d0,d1,iv} into CcI; 16-pair tiles: pinned BH gathers, broadcast-
// read R-build (no shuffles), MFMA, epilogue; in-block close.
// ---------------------------------------------------------------------------
__global__ __launch_bounds__(512, 4) void gat_kernel(
    const int* __restrict__ nei, const float2v* __restrict__ corr2,
    const float* __restrict__ A_pre, const float2v* __restrict__ BH,
    const float4v* __restrict__ KT, const float2v* __restrict__ GB,
    const float* __restrict__ evec, const unsigned short* __restrict__ WgT,
    const float* __restrict__ hidden, const float* __restrict__ cn,
    const float* __restrict__ bea, const float* __restrict__ Ww,
    const float* __restrict__ bw, const float* __restrict__ gw,
    const float* __restrict__ bew, float* __restrict__ out) {
  __shared__ unsigned short Lst[NN + 16];
  __shared__ __align__(16) float4v CcI[NN + 16];  // {iv*c0, iv*c1, iv, 0}
  __shared__ __align__(16) unsigned short Rt[8][16 * 72];  // per-wave slice
  __shared__ float red[8][DD];
  __shared__ int cLds;

  const int i = blockIdx.x;
  const int tid = threadIdx.x;
  const int wid = tid >> 6;
  const int lane = tid & 63;
  const int quad = lane >> 4;
  const int nl = lane & 15;

  // Uniform moments (SGPR loads; needed by compaction, no VGPR pressure).
  const float e00 = evec[0], e11 = evec[1], ebb = evec[2];
  const float e01 = evec[3], e0b = evec[4], e1b = evec[5];

  if (tid == 0) cLds = 0;
  __syncthreads();
  {
    int jj = tid;  // 0..511, always < NN
    if (nei[i * NN + jj] > 0) {
      int idx = atomicAdd(&cLds, 1);
      Lst[idx] = (unsigned short)jj;
      float2v cc = corr2[i * NN + jj];
      float var = cc[0] * cc[0] * e00 + cc[1] * cc[1] * e11 + ebb +
                  2.f * (cc[0] * cc[1] * e01 + cc[0] * e0b + cc[1] * e1b);
      float iv = __builtin_amdgcn_rsqf(var + EPSF);
      float4v ci;
      ci[0] = iv * cc[0];
      ci[1] = iv * cc[1];
      ci[2] = iv;
      ci[3] = 0.f;
      CcI[idx] = ci;
    }
    jj = tid + 512;  // 512..1023: guard against running past row i
    if (jj < NN && nei[i * NN + jj] > 0) {
      int idx = atomicAdd(&cLds, 1);
      Lst[idx] = (unsigned short)jj;
      float2v cc = corr2[i * NN + jj];
      float var = cc[0] * cc[0] * e00 + cc[1] * cc[1] * e11 + ebb +
                  2.f * (cc[0] * cc[1] * e01 + cc[0] * e0b + cc[1] * e1b);
      float iv = __builtin_amdgcn_rsqf(var + EPSF);
      float4v ci;
      ci[0] = iv * cc[0];
      ci[1] = iv * cc[1];
      ci[2] = iv;
      ci[3] = 0.f;
      CcI[idx] = ci;
    }
  }
  __syncthreads();
  const int cnt = cLds;
  if (cnt > 0 && tid < 16) {  // tail pad: no clamps in the tile loop
    Lst[cnt + tid] = Lst[0];
    CcI[cnt + tid] = CcI[0];
  }

  // Uniform constants (loaded AFTER compaction: VGPR live ranges must not
  // span the barriers above — r12 proved that spills).
  const float4v kt = KT[lane];  // k = lane: {gr*w0h, gr*w1h, gr*bh, ber}

  // B fragments of Wg_lo (16B contiguous from transposed pack).
  short8 Bf[2][4];
#pragma unroll
  for (int ks = 0; ks < 2; ++ks)
#pragma unroll
    for (int nt = 0; nt < 4; ++nt)
      __builtin_memcpy(&Bf[ks][nt],
                       &WgT[(nt * 16 + nl) * DD + ks * 32 + quad * 8], 16);

  float ngg[4], nbeg[4], pre4[4];
#pragma unroll
  for (int nt = 0; nt < 4; ++nt) {
    int d = nt * 16 + nl;
    float2v gb = GB[d];
    ngg[nt] = gb[0];   // -log2e * gg
    nbeg[nt] = gb[1];  // -log2e * beg
    pre4[nt] = A_pre[i * DD + d];
  }

  float accT[4] = {0.f, 0.f, 0.f, 0.f};
  __syncthreads();  // pad visible to all waves

  for (int base = wid * 16; base < cnt; base += 128) {
    // --- Issue phase: pair ids + ALL 16 BH gathers, pinned early so their
    // latency hides under the R-build + MFMAs below.
    ushort4v l4;
    __builtin_memcpy(&l4, &Lst[base + quad * 4], 8);
    float2v bh[4][4];
#pragma unroll
    for (int rr = 0; rr < 4; ++rr) {
      const int jpr = (int)l4[rr];
#pragma unroll
      for (int nt = 0; nt < 4; ++nt) bh[rr][nt] = BH[jpr * DD + nt * 16 + nl];
    }
    asm volatile("" ::: "memory");  // pin: loads above may not sink below

    // R build: lane==k; pair q's {d0,d1,iv} via broadcast ds_read_b128
    // (same address across lanes = conflict-free). Grouped 4x4 with
    // scheduling barriers so the reads can't all hoist (spill guard).
#pragma unroll
    for (int g = 0; g < 4; ++g) {
#pragma unroll
      for (int t = 0; t < 4; ++t) {
        const int q = g * 4 + t;
        float4v ci = CcI[base + q];
        float r = fmaf(ci[0], kt[0],
                       fmaf(ci[1], kt[1], fmaf(ci[2], kt[2], kt[3])));
        Rt[wid][q * 72 + lane] = f2bf(fmaxf(0.f, r));
      }
      asm volatile("" ::: "memory");
    }

    short8 a0, a1;
    __builtin_memcpy(&a0, &Rt[wid][nl * 72 + quad * 8], 16);
    __builtin_memcpy(&a1, &Rt[wid][nl * 72 + 32 + quad * 8], 16);
    float4v acc[4];
#pragma unroll
    for (int nt = 0; nt < 4; ++nt) {
      float4v z = {0.f, 0.f, 0.f, 0.f};
      z = __builtin_amdgcn_mfma_f32_16x16x32_bf16(a0, Bf[0][nt], z, 0, 0, 0);
      z = __builtin_amdgcn_mfma_f32_16x16x32_bf16(a1, Bf[1][nt], z, 0, 0, 0);
      acc[nt] = z;
    }

    // Epilogue: per-C-row LN + sigmoid gate + accumulate gate*h[j].
#pragma unroll
    for (int rr = 0; rr < 4; ++rr) {
      const float pvr = (base + quad * 4 + rr < cnt) ? 1.f : 0.f;
      float y0 = acc[0][rr] + pre4[0] + bh[rr][0][0];
      float y1 = acc[1][rr] + pre4[1] + bh[rr][1][0];
      float y2 = acc[2][rr] + pre4[2] + bh[rr][2][0];
      float y3 = acc[3][rr] + pre4[3] + bh[rr][3][0];
      float s = y0 + y1 + y2 + y3;
      float qq = y0 * y0 + y1 * y1 + y2 * y2 + y3 * y3;
#pragma unroll
      for (int m = 1; m < 16; m <<= 1) {
        s += __shfl_xor(s, m);
        qq += __shfl_xor(qq, m);
      }
      float u = s * (1.f / DD);
      float vv = qq * (1.f / DD) - u * u;
      float inv = __builtin_amdgcn_rsqf(vv + EPSF);
      float g0 = __builtin_amdgcn_exp2f(fmaf(ngg[0] * (y0 - u), inv, nbeg[0]));
      float g1 = __builtin_amdgcn_exp2f(fmaf(ngg[1] * (y1 - u), inv, nbeg[1]));
      float g2 = __builtin_amdgcn_exp2f(fmaf(ngg[2] * (y2 - u), inv, nbeg[2]));
      float g3 = __builtin_amdgcn_exp2f(fmaf(ngg[3] * (y3 - u), inv, nbeg[3]));
      accT[0] =
          fmaf(__builtin_amdgcn_rcpf(1.f + g0) * pvr, bh[rr][0][1], accT[0]);
      accT[1] =
          fmaf(__builtin_amdgcn_rcpf(1.f + g1) * pvr, bh[rr][1][1], accT[1]);
      accT[2] =
          fmaf(__builtin_amdgcn_rcpf(1.f + g2) * pvr, bh[rr][2][1], accT[2]);
      accT[3] =
          fmaf(__builtin_amdgcn_rcpf(1.f + g3) * pvr, bh[rr][3][1], accT[3]);
    }
  }

  // Per-wave partials -> LDS (all 8 waves reach here).
#pragma unroll
  for (int nt = 0; nt < 4; ++nt) {
    accT[nt] += __shfl_xor(accT[nt], 16);
    accT[nt] += __shfl_xor(accT[nt], 32);
  }
  if (lane < 16) {
#pragma unroll
    for (int nt = 0; nt < 4; ++nt) red[wid][nt * 16 + nl] = accT[nt];
  }
  __syncthreads();

  if (tid < 64) {  // wave 0 closes the row
    const int d = tid;
    float hs = 0.f;
#pragma unroll
    for (int w = 0; w < 8; ++w) hs += red[w][d];
    float tta = fmaxf(bea[0], 0.f);
    float wgt = (tta > 0.f && cnt > 0) ? __builtin_amdgcn_rcpf((float)cnt)
                                       : (1.f / (float)NN);
    hs *= wgt;  // H_sum[i][d]

    float dotv = bw[d];
#pragma unroll 8
    for (int k = 0; k < DD; ++k) {
      float hk = __shfl(hs, k);
      dotv = fmaf(hk, Ww[k * DD + d], dotv);
    }
    float s = dotv, qq = dotv * dotv;
#pragma unroll
    for (int m = 1; m < 64; m <<= 1) {
      s += __shfl_xor(s, m);
      qq += __shfl_xor(qq, m);
    }
    float u = s * (1.f / DD);
    float var2 = qq * (1.f / DD) - u * u;
    float inv = __builtin_amdgcn_rsqf(var2 + EPSF);
    float val = fmaxf(0.f, fmaf(gw[d], (dotv - u) * inv, bew[d]));
    float Cv = val + cn[i * DD + d];
    out[i * DD + d] = hidden[i * DD + d] + fast_tanh(Cv);
    out[NN * DD + i * DD + d] = Cv;
  }
}

extern "C" void kernel_launch(void* const* d_in, const int* in_sizes, int n_in,
                              void* d_out, int out_size, void* d_ws,
                              size_t ws_size, hipStream_t stream) {
  const float* corr = (const float*)d_in[0];
  const int* nei = (const int*)d_in[1];
  // d_in[2] nei_num: unused by the reference math
  const float* hidden = (const float*)d_in[3];
  const float* cn = (const float*)d_in[4];
  const float* Wr = (const float*)d_in[5];
  const float* br = (const float*)d_in[6];
  const float* gr = (const float*)d_in[7];
  const float* ber = (const float*)d_in[8];
  const float* Wg = (const float*)d_in[9];
  const float* bg = (const float*)d_in[10];
  const float* gg = (const float*)d_in[11];
  const float* beg = (const float*)d_in[12];
  // d_in[13..15] W_a/b_a/g_a: cancel analytically
  const float* bea = (const float*)d_in[16];
  const float* Ww = (const float*)d_in[17];
  const float* bw = (const float*)d_in[18];
  const float* gw = (const float*)d_in[19];
  const float* bew = (const float*)d_in[20];
  float* out = (float*)d_out;

  float* ws = (float*)d_ws;
  float* A_pre = ws;                                     // 49152 floats
  float2v* BH = (float2v*)(ws + 49152);                  // 98304 floats
  float4v* KT = (float4v*)(ws + 147456);                 // 256 floats
  float2v* GB = (float2v*)(ws + 147712);                 // 128 floats
  float* evec = ws + 147840;                             // 16 floats
  unsigned short* WgT = (unsigned short*)(ws + 147856);  // 4096 shorts

  prep_kernel<<<NN + 1, 256, 0, stream>>>(hidden, Wg, bg, Wr, br, gr, ber, gg,
                                          beg, A_pre, BH, KT, GB, evec, WgT);
  gat_kernel<<<NN, 512, 0, stream>>>((const int*)nei, (const float2v*)corr,
                                     A_pre, BH, KT, GB, evec, WgT, hidden, cn,
                                     bea, Ww, bw, gw, bew, out);
}